// Round 1
// baseline (1307.455 us; speedup 1.0000x reference)
//
#include <hip/hip_runtime.h>
#include <cstdint>
#include <cstddef>

#define NNODES 100000
#define NEDGES 1600000
// D = 128, C = 128 (hard-coded below)

// ---------------------------------------------------------------- utilities

__global__ void zero_int_kernel(int* __restrict__ p, int n) {
  int i = blockIdx.x * blockDim.x + threadIdx.x;
  if (i < n) p[i] = 0;
}

// Decide whether edge_index is int64 or int32.
// If int64 (values < 2^31), the odd 32-bit words (high halves) are all zero.
// If int32, odd words are random src indices -> almost surely some nonzero.
__global__ void detect_kernel(const unsigned int* __restrict__ ei, int* __restrict__ flag) {
  unsigned int v = ei[2 * threadIdx.x + 1];
  unsigned long long b = __ballot(v != 0u);
  if (threadIdx.x == 0) *flag = (b == 0ull) ? 1 : 0;
}

__device__ __forceinline__ int edge_val(const void* ei, int is64, long long idx) {
  if (is64) return (int)((const long long*)ei)[idx];
  return ((const int*)ei)[idx];
}

// ---------------------------------------------------------------- degree / CSR

__global__ void hist_kernel(const void* __restrict__ ei, const int* __restrict__ flag,
                            int* __restrict__ counts) {
  const int is64 = *flag;
  for (long long e = (long long)blockIdx.x * blockDim.x + threadIdx.x; e < NEDGES;
       e += (long long)gridDim.x * blockDim.x) {
    int d = edge_val(ei, is64, NEDGES + e);
    atomicAdd(&counts[d], 1);
  }
}

__global__ void dinv_kernel(const int* __restrict__ counts, float* __restrict__ dinv) {
  int i = blockIdx.x * blockDim.x + threadIdx.x;
  if (i < NNODES) dinv[i] = rsqrtf((float)(counts[i] + 1));  // +1 self loop
}

#define SCAN_B 256
#define SCAN_TILE 1024

__global__ void scan_reduce_kernel(const int* __restrict__ counts, int* __restrict__ bsums) {
  __shared__ int sd[SCAN_B];
  int t = threadIdx.x;
  int base = blockIdx.x * SCAN_TILE + t * 4;
  int s = 0;
#pragma unroll
  for (int i = 0; i < 4; i++) {
    int idx = base + i;
    if (idx < NNODES) s += counts[idx];
  }
  sd[t] = s;
  __syncthreads();
  for (int o = SCAN_B / 2; o > 0; o >>= 1) {
    if (t < o) sd[t] += sd[t + o];
    __syncthreads();
  }
  if (t == 0) bsums[blockIdx.x] = sd[0];
}

__global__ void scan_bsums_kernel(int* __restrict__ bsums, int* __restrict__ offs, int nb) {
  if (threadIdx.x == 0 && blockIdx.x == 0) {
    int run = 0;
    for (int b = 0; b < nb; b++) {
      int v = bsums[b];
      bsums[b] = run;
      run += v;
    }
    offs[NNODES] = run;
  }
}

__global__ void scan_write_kernel(const int* __restrict__ counts, const int* __restrict__ bsums,
                                  int* __restrict__ offs) {
  __shared__ int sd[SCAN_B];
  int t = threadIdx.x;
  int base = blockIdx.x * SCAN_TILE + t * 4;
  int v[4];
  int s = 0;
#pragma unroll
  for (int i = 0; i < 4; i++) {
    int idx = base + i;
    v[i] = (idx < NNODES) ? counts[idx] : 0;
    s += v[i];
  }
  sd[t] = s;
  __syncthreads();
  for (int o = 1; o < SCAN_B; o <<= 1) {
    int x = (t >= o) ? sd[t - o] : 0;
    __syncthreads();
    sd[t] += x;
    __syncthreads();
  }
  int run = sd[t] - s + bsums[blockIdx.x];
#pragma unroll
  for (int i = 0; i < 4; i++) {
    int idx = base + i;
    if (idx < NNODES) {
      offs[idx] = run;
      run += v[i];
    }
  }
}

__global__ void fill_kernel(const void* __restrict__ ei, const int* __restrict__ flag,
                            const int* __restrict__ offs, int* __restrict__ fillc,
                            int* __restrict__ csr) {
  const int is64 = *flag;
  for (long long e = (long long)blockIdx.x * blockDim.x + threadIdx.x; e < NEDGES;
       e += (long long)gridDim.x * blockDim.x) {
    int s = edge_val(ei, is64, e);
    int d = edge_val(ei, is64, NEDGES + e);
    int pos = offs[d] + atomicAdd(&fillc[d], 1);
    csr[pos] = s;
  }
}

// ---------------------------------------------------------------- aggregation (gather)
// out[i,:] = dinv[i] * sum_{j in nbr(i)} dinv[j]*in[j,:] + dinv[i]^2 * in[i,:] (+ bias)
// M = 128 fixed. One wave per node, float2 per lane.

__global__ __launch_bounds__(256) void aggregate_kernel(
    const float* __restrict__ in, float* __restrict__ out, const int* __restrict__ offs,
    const int* __restrict__ csr, const float* __restrict__ dinv, const float* __restrict__ bias) {
  int node = blockIdx.x * 4 + (threadIdx.x >> 6);
  if (node >= NNODES) return;
  int c = (threadIdx.x & 63) * 2;
  float2 acc = make_float2(0.f, 0.f);
  int beg = offs[node], end = offs[node + 1];
  for (int p = beg; p < end; ++p) {
    int j = csr[p];
    float dj = dinv[j];
    float2 v = *(const float2*)(in + (size_t)j * 128 + c);
    acc.x += dj * v.x;
    acc.y += dj * v.y;
  }
  float di = dinv[node];
  float2 s = *(const float2*)(in + (size_t)node * 128 + c);
  float2 r;
  r.x = di * acc.x + di * di * s.x;
  r.y = di * acc.y + di * di * s.y;
  if (bias) {
    r.x += bias[c];
    r.y += bias[c + 1];
  }
  *(float2*)(out + (size_t)node * 128 + c) = r;
}

// ---------------------------------------------------------------- fp32 GEMM
// C[n,M] = concat(A0,A1,A2; widths K0,K1,K2) @ W[Ktot,M] (+bias) (+relu)
// Tile 128x128, BK=16, 256 threads, 8x8 micro-tile (as 2x2 groups of 4x4).

#define BM 128
#define BN 128
#define BK 16

__global__ __launch_bounds__(256) void gemm_kernel(
    const float* __restrict__ A0, int K0, const float* __restrict__ A1, int K1,
    const float* __restrict__ A2, int K2, const float* __restrict__ W, int M,
    const float* __restrict__ bias, float* __restrict__ Cmat, int relu, int nrows) {
  __shared__ __align__(16) float As[BK][BM + 4];
  __shared__ __align__(16) float Ws[BK][BN];
  const int tid = threadIdx.x;
  const int tx4 = (tid & 15) * 4;
  const int ty4 = ((tid >> 4) & 15) * 4;
  const int rowBase = blockIdx.x * BM;
  const int colBase = blockIdx.y * BN;
  const int Ktot = K0 + K1 + K2;

  float acc[8][8];
#pragma unroll
  for (int i = 0; i < 8; i++)
#pragma unroll
    for (int j = 0; j < 8; j++) acc[i][j] = 0.f;

  const int ar = tid >> 2;        // 0..63
  const int ak = (tid & 3) * 4;   // 0,4,8,12
  const int wr = tid >> 4;        // 0..15
  const int wc = (tid & 15) * 4;  // 0..60

  for (int k0 = 0; k0 < Ktot; k0 += BK) {
    const float* Ap;
    int kl, Kp;
    if (k0 < K0) {
      Ap = A0; kl = k0; Kp = K0;
    } else if (k0 < K0 + K1) {
      Ap = A1; kl = k0 - K0; Kp = K1;
    } else {
      Ap = A2; kl = k0 - K0 - K1; Kp = K2;
    }
    {
      int r = rowBase + ar;
      float4 v = make_float4(0.f, 0.f, 0.f, 0.f);
      if (r < nrows) v = *(const float4*)(Ap + (size_t)r * Kp + kl + ak);
      As[ak + 0][ar] = v.x;
      As[ak + 1][ar] = v.y;
      As[ak + 2][ar] = v.z;
      As[ak + 3][ar] = v.w;
      int r2 = rowBase + 64 + ar;
      float4 v2 = make_float4(0.f, 0.f, 0.f, 0.f);
      if (r2 < nrows) v2 = *(const float4*)(Ap + (size_t)r2 * Kp + kl + ak);
      As[ak + 0][64 + ar] = v2.x;
      As[ak + 1][64 + ar] = v2.y;
      As[ak + 2][64 + ar] = v2.z;
      As[ak + 3][64 + ar] = v2.w;
      float4 w0 = *(const float4*)(W + (size_t)(k0 + wr) * M + colBase + wc);
      *(float4*)&Ws[wr][wc] = w0;
      float4 w1 = *(const float4*)(W + (size_t)(k0 + wr) * M + colBase + 64 + wc);
      *(float4*)&Ws[wr][64 + wc] = w1;
    }
    __syncthreads();
#pragma unroll
    for (int kk = 0; kk < BK; ++kk) {
      float a[8], b[8];
      *(float4*)&a[0] = *(const float4*)&As[kk][ty4];
      *(float4*)&a[4] = *(const float4*)&As[kk][64 + ty4];
      *(float4*)&b[0] = *(const float4*)&Ws[kk][tx4];
      *(float4*)&b[4] = *(const float4*)&Ws[kk][64 + tx4];
#pragma unroll
      for (int i = 0; i < 8; i++)
#pragma unroll
        for (int j = 0; j < 8; j++) acc[i][j] += a[i] * b[j];
    }
    __syncthreads();
  }

  float4 b0 = make_float4(0.f, 0.f, 0.f, 0.f), b1 = b0;
  if (bias) {
    b0 = *(const float4*)(bias + colBase + tx4);
    b1 = *(const float4*)(bias + colBase + 64 + tx4);
  }
#pragma unroll
  for (int i = 0; i < 8; i++) {
    int r = rowBase + ((i < 4) ? (ty4 + i) : (64 + ty4 + (i - 4)));
    if (r >= nrows) continue;
    float4 v0, v1;
    v0.x = acc[i][0] + b0.x;
    v0.y = acc[i][1] + b0.y;
    v0.z = acc[i][2] + b0.z;
    v0.w = acc[i][3] + b0.w;
    v1.x = acc[i][4] + b1.x;
    v1.y = acc[i][5] + b1.y;
    v1.z = acc[i][6] + b1.z;
    v1.w = acc[i][7] + b1.w;
    if (relu) {
      v0.x = fmaxf(v0.x, 0.f); v0.y = fmaxf(v0.y, 0.f);
      v0.z = fmaxf(v0.z, 0.f); v0.w = fmaxf(v0.w, 0.f);
      v1.x = fmaxf(v1.x, 0.f); v1.y = fmaxf(v1.y, 0.f);
      v1.z = fmaxf(v1.z, 0.f); v1.w = fmaxf(v1.w, 0.f);
    }
    *(float4*)(Cmat + (size_t)r * M + colBase + tx4) = v0;
    *(float4*)(Cmat + (size_t)r * M + colBase + 64 + tx4) = v1;
  }
}

// ---------------------------------------------------------------- launch

extern "C" void kernel_launch(void* const* d_in, const int* in_sizes, int n_in, void* d_out,
                              int out_size, void* d_ws, size_t ws_size, hipStream_t stream) {
  const float* x_self     = (const float*)d_in[0];
  const float* x_neighbor = (const float*)d_in[1];
  const void*  edge_index = d_in[2];
  const float* W_in_self  = (const float*)d_in[3];
  const float* b_in_self  = (const float*)d_in[4];
  const float* W_out_self = (const float*)d_in[5];
  const float* b_out_self = (const float*)d_in[6];
  const float* Wg1        = (const float*)d_in[7];
  const float* bg1        = (const float*)d_in[8];
  const float* Wg2        = (const float*)d_in[9];
  const float* bg2        = (const float*)d_in[10];
  const float* W_out      = (const float*)d_in[11];
  const float* b_out      = (const float*)d_in[12];
  float* out = (float*)d_out;

  // workspace layout (256B-aligned slices)
  char* ws = (char*)d_ws;
  size_t off = 0;
  auto alloc = [&](size_t bytes) -> void* {
    void* p = ws + off;
    off = (off + bytes + 255) & ~(size_t)255;
    return p;
  };
  int*   counts = (int*)alloc((size_t)NNODES * 4);
  int*   fillc  = (int*)alloc((size_t)NNODES * 4);
  int*   offs   = (int*)alloc((size_t)(NNODES + 1) * 4);
  int*   csr    = (int*)alloc((size_t)NEDGES * 4);
  int*   bsums  = (int*)alloc(4096);
  int*   flag   = (int*)alloc(256);
  float* dinv   = (float*)alloc((size_t)NNODES * 4);
  float* bufA   = (float*)alloc((size_t)NNODES * 256 * 4);
  float* bufB   = (float*)alloc((size_t)NNODES * 256 * 4);
  (void)ws_size;

  const int nb = (NNODES + SCAN_TILE - 1) / SCAN_TILE;  // 98
  const int gridRows = (NNODES + BM - 1) / BM;          // 782

  detect_kernel<<<1, 64, 0, stream>>>((const unsigned int*)edge_index, flag);
  zero_int_kernel<<<(NNODES + 255) / 256, 256, 0, stream>>>(counts, NNODES);
  zero_int_kernel<<<(NNODES + 255) / 256, 256, 0, stream>>>(fillc, NNODES);
  hist_kernel<<<1024, 256, 0, stream>>>(edge_index, flag, counts);
  dinv_kernel<<<(NNODES + 255) / 256, 256, 0, stream>>>(counts, dinv);
  scan_reduce_kernel<<<nb, SCAN_B, 0, stream>>>(counts, bsums);
  scan_bsums_kernel<<<1, 64, 0, stream>>>(bsums, offs, nb);
  scan_write_kernel<<<nb, SCAN_B, 0, stream>>>(counts, bsums, offs);
  fill_kernel<<<1024, 256, 0, stream>>>(edge_index, flag, offs, fillc, csr);

  // ---- dense self branch ----
  // l1relu = relu(x_self @ W_in_self + b_in_self)  -> bufA [N,256]
  gemm_kernel<<<dim3(gridRows, 2), 256, 0, stream>>>(x_self, 128, nullptr, 0, nullptr, 0,
                                                     W_in_self, 256, b_in_self, bufA, 1, NNODES);
  // out1 = [x_self, l1relu] @ W_out_self + b_out_self -> d_out[0 : N*128]
  gemm_kernel<<<dim3(gridRows, 1), 256, 0, stream>>>(x_self, 128, bufA, 256, nullptr, 0,
                                                     W_out_self, 128, b_out_self, out, 0, NNODES);

  // ---- GCN branch (A_norm @ (X W) == (A_norm @ X) W) ----
  float* aggx = bufA;                            // [N,128] (bufA reusable now)
  float* g1   = bufB;                            // [N,256]
  float* xw2  = bufA;                            // [N,128]
  float* g2   = bufA + (size_t)NNODES * 128;     // [N,128]

  aggregate_kernel<<<NNODES / 4, 256, 0, stream>>>(x_neighbor, aggx, offs, csr, dinv, nullptr);
  gemm_kernel<<<dim3(gridRows, 2), 256, 0, stream>>>(aggx, 128, nullptr, 0, nullptr, 0, Wg1, 256,
                                                     bg1, g1, 0, NNODES);
  gemm_kernel<<<dim3(gridRows, 1), 256, 0, stream>>>(g1, 256, nullptr, 0, nullptr, 0, Wg2, 128,
                                                     nullptr, xw2, 0, NNODES);
  aggregate_kernel<<<NNODES / 4, 256, 0, stream>>>(xw2, g2, offs, csr, dinv, bg2);
  // out2 = [x_neighbor, g1, g2] @ W_out + b_out -> d_out[N*128 : 2*N*128]
  gemm_kernel<<<dim3(gridRows, 1), 256, 0, stream>>>(x_neighbor, 128, g1, 256, g2, 128, W_out, 128,
                                                     b_out, out + (size_t)NNODES * 128, 0, NNODES);
}

// Round 2
// 1037.645 us; speedup vs baseline: 1.2600x; 1.2600x over previous
//
#include <hip/hip_runtime.h>
#include <cstdint>
#include <cstddef>

#define NNODES 100000
#define NEDGES 1600000
// D = 128, C = 128 (hard-coded below)

typedef short bf16x8 __attribute__((ext_vector_type(8)));
typedef float f32x4 __attribute__((ext_vector_type(4)));

// ---------------------------------------------------------------- bf16 split helpers

__device__ __forceinline__ unsigned short bf16_rne(float x) {
  unsigned int u = __float_as_uint(x);
  unsigned int r = u + 0x7FFFu + ((u >> 16) & 1u);
  return (unsigned short)(r >> 16);
}
__device__ __forceinline__ float bf16_to_f(unsigned short h) {
  return __uint_as_float(((unsigned int)h) << 16);
}

// ---------------------------------------------------------------- utilities

__global__ void zero_int_kernel(int* __restrict__ p, int n) {
  int i = blockIdx.x * blockDim.x + threadIdx.x;
  if (i < n) p[i] = 0;
}

// int64 vs int32 edge_index detection (high words all zero => int64)
__global__ void detect_kernel(const unsigned int* __restrict__ ei, int* __restrict__ flag) {
  unsigned int v = ei[2 * threadIdx.x + 1];
  unsigned long long b = __ballot(v != 0u);
  if (threadIdx.x == 0) *flag = (b == 0ull) ? 1 : 0;
}

__device__ __forceinline__ int edge_val(const void* ei, int is64, long long idx) {
  if (is64) return (int)((const long long*)ei)[idx];
  return ((const int*)ei)[idx];
}

// ---------------------------------------------------------------- degree / CSR

__global__ void hist_kernel(const void* __restrict__ ei, const int* __restrict__ flag,
                            int* __restrict__ counts) {
  const int is64 = *flag;
  for (long long e = (long long)blockIdx.x * blockDim.x + threadIdx.x; e < NEDGES;
       e += (long long)gridDim.x * blockDim.x) {
    int d = edge_val(ei, is64, NEDGES + e);
    atomicAdd(&counts[d], 1);
  }
}

__global__ void dinv_kernel(const int* __restrict__ counts, float* __restrict__ dinv) {
  int i = blockIdx.x * blockDim.x + threadIdx.x;
  if (i < NNODES) dinv[i] = rsqrtf((float)(counts[i] + 1));  // +1 self loop
}

#define SCAN_B 256
#define SCAN_TILE 1024

__global__ void scan_reduce_kernel(const int* __restrict__ counts, int* __restrict__ bsums) {
  __shared__ int sd[SCAN_B];
  int t = threadIdx.x;
  int base = blockIdx.x * SCAN_TILE + t * 4;
  int s = 0;
#pragma unroll
  for (int i = 0; i < 4; i++) {
    int idx = base + i;
    if (idx < NNODES) s += counts[idx];
  }
  sd[t] = s;
  __syncthreads();
  for (int o = SCAN_B / 2; o > 0; o >>= 1) {
    if (t < o) sd[t] += sd[t + o];
    __syncthreads();
  }
  if (t == 0) bsums[blockIdx.x] = sd[0];
}

__global__ void scan_bsums_kernel(int* __restrict__ bsums, int* __restrict__ offs, int nb) {
  if (threadIdx.x == 0 && blockIdx.x == 0) {
    int run = 0;
    for (int b = 0; b < nb; b++) {
      int v = bsums[b];
      bsums[b] = run;
      run += v;
    }
    offs[NNODES] = run;
  }
}

__global__ void scan_write_kernel(const int* __restrict__ counts, const int* __restrict__ bsums,
                                  int* __restrict__ offs) {
  __shared__ int sd[SCAN_B];
  int t = threadIdx.x;
  int base = blockIdx.x * SCAN_TILE + t * 4;
  int v[4];
  int s = 0;
#pragma unroll
  for (int i = 0; i < 4; i++) {
    int idx = base + i;
    v[i] = (idx < NNODES) ? counts[idx] : 0;
    s += v[i];
  }
  sd[t] = s;
  __syncthreads();
  for (int o = 1; o < SCAN_B; o <<= 1) {
    int x = (t >= o) ? sd[t - o] : 0;
    __syncthreads();
    sd[t] += x;
    __syncthreads();
  }
  int run = sd[t] - s + bsums[blockIdx.x];
#pragma unroll
  for (int i = 0; i < 4; i++) {
    int idx = base + i;
    if (idx < NNODES) {
      offs[idx] = run;
      run += v[i];
    }
  }
}

__global__ void fill_kernel(const void* __restrict__ ei, const int* __restrict__ flag,
                            const int* __restrict__ offs, int* __restrict__ fillc,
                            int* __restrict__ csr) {
  const int is64 = *flag;
  for (long long e = (long long)blockIdx.x * blockDim.x + threadIdx.x; e < NEDGES;
       e += (long long)gridDim.x * blockDim.x) {
    int s = edge_val(ei, is64, e);
    int d = edge_val(ei, is64, NEDGES + e);
    int pos = offs[d] + atomicAdd(&fillc[d], 1);
    csr[pos] = s;
  }
}

// ---------------------------------------------------------------- aggregation (gather)
// out[i,:] = dinv[i] * sum_{j in nbr(i)} dinv[j]*in[j,:] + dinv[i]^2 * in[i,:] (+ bias)

__global__ __launch_bounds__(256) void aggregate_kernel(
    const float* __restrict__ in, float* __restrict__ out, const int* __restrict__ offs,
    const int* __restrict__ csr, const float* __restrict__ dinv, const float* __restrict__ bias) {
  int node = blockIdx.x * 4 + (threadIdx.x >> 6);
  if (node >= NNODES) return;
  int c = (threadIdx.x & 63) * 2;
  float2 acc = make_float2(0.f, 0.f);
  int beg = offs[node], end = offs[node + 1];
  for (int p = beg; p < end; ++p) {
    int j = csr[p];
    float dj = dinv[j];
    float2 v = *(const float2*)(in + (size_t)j * 128 + c);
    acc.x += dj * v.x;
    acc.y += dj * v.y;
  }
  float di = dinv[node];
  float2 s = *(const float2*)(in + (size_t)node * 128 + c);
  float2 r;
  r.x = di * acc.x + di * di * s.x;
  r.y = di * acc.y + di * di * s.y;
  if (bias) {
    r.x += bias[c];
    r.y += bias[c + 1];
  }
  *(float2*)(out + (size_t)node * 128 + c) = r;
}

// ---------------------------------------------------------------- weight prep
// W [K][M] fp32  ->  Wt_hi/Wt_lo [M][K] bf16 (transposed, split)

__global__ void wprep_kernel(const float* __restrict__ W, int K, int M,
                             unsigned short* __restrict__ th, unsigned short* __restrict__ tl) {
  int i = blockIdx.x * blockDim.x + threadIdx.x;
  if (i >= K * M) return;
  int k = i / M, m = i - k * M;
  float x = W[i];
  unsigned short h = bf16_rne(x);
  float lo = x - bf16_to_f(h);
  th[(size_t)m * K + k] = h;
  tl[(size_t)m * K + k] = bf16_rne(lo);
}

// ---------------------------------------------------------------- bf16x3 split MFMA GEMM
// C[n,M] = concat(A0,A1,A2) @ W (+bias)(+relu), fp32 in/out, internally bf16 hi/lo split:
// x*w ~= xh*wh + xh*wl + xl*wh (fp32 MFMA accumulation). Error ~2^-16 relative.
// Block 128x128, BK=32, 4 waves each 64x64 (4x4 tiles of 16x16x32 MFMA).
// LDS rows padded to 40 bf16 (80 B): b128 fragment reads are <=2-way on banks (free).

#define BM 128
#define BN 128
#define BK 32
#define LDT 40

__global__ __launch_bounds__(256) void gemm_mfma_kernel(
    const float* __restrict__ A0, int K0, const float* __restrict__ A1, int K1,
    const float* __restrict__ A2, int K2, const unsigned short* __restrict__ Bth,
    const unsigned short* __restrict__ Btl, int Ktot, int M, const float* __restrict__ bias,
    float* __restrict__ Cmat, int relu, int nrows) {
  __shared__ unsigned short As_hi[BM * LDT];
  __shared__ unsigned short As_lo[BM * LDT];
  __shared__ unsigned short Bs_hi[BN * LDT];
  __shared__ unsigned short Bs_lo[BN * LDT];

  const int tid = threadIdx.x;
  const int lane = tid & 63;
  const int wv = tid >> 6;
  const int mBase = (wv >> 1) * 64;
  const int nBase = (wv & 1) * 64;
  const int ml = lane & 15;
  const int quad = lane >> 4;
  const int rowBase = blockIdx.x * BM;
  const int colBase = blockIdx.y * BN;

  // staging assignment: thread handles one row-half (16 k values)
  const int sr = tid >> 1;        // 0..127
  const int skc = (tid & 1) * 16; // 0 or 16

  f32x4 acc[4][4];
  const f32x4 zero = {0.f, 0.f, 0.f, 0.f};
#pragma unroll
  for (int i = 0; i < 4; i++)
#pragma unroll
    for (int j = 0; j < 4; j++) acc[i][j] = zero;

  for (int k0 = 0; k0 < Ktot; k0 += BK) {
    // ---- stage A (fp32 -> hi/lo bf16) ----
    const float* Ap;
    int kl, Kp;
    if (k0 < K0) {
      Ap = A0; kl = k0; Kp = K0;
    } else if (k0 < K0 + K1) {
      Ap = A1; kl = k0 - K0; Kp = K1;
    } else {
      Ap = A2; kl = k0 - K0 - K1; Kp = K2;
    }
    {
      int gr = rowBase + sr;
      float4 v[4];
      if (gr < nrows) {
        const float4* src = (const float4*)(Ap + (size_t)gr * Kp + kl + skc);
#pragma unroll
        for (int i = 0; i < 4; i++) v[i] = src[i];
      } else {
#pragma unroll
        for (int i = 0; i < 4; i++) v[i] = make_float4(0.f, 0.f, 0.f, 0.f);
      }
      unsigned short hb[16], lb[16];
      const float* vf = (const float*)v;
#pragma unroll
      for (int i = 0; i < 16; i++) {
        float x = vf[i];
        unsigned short h = bf16_rne(x);
        hb[i] = h;
        lb[i] = bf16_rne(x - bf16_to_f(h));
      }
      *(uint4*)&As_hi[sr * LDT + skc] = *(uint4*)&hb[0];
      *(uint4*)&As_hi[sr * LDT + skc + 8] = *(uint4*)&hb[8];
      *(uint4*)&As_lo[sr * LDT + skc] = *(uint4*)&lb[0];
      *(uint4*)&As_lo[sr * LDT + skc + 8] = *(uint4*)&lb[8];

      // ---- stage B (pre-split bf16, [n][Ktot] layout) ----
      const unsigned short* bh = Bth + (size_t)(colBase + sr) * Ktot + k0 + skc;
      const unsigned short* bl = Btl + (size_t)(colBase + sr) * Ktot + k0 + skc;
      uint4 u0 = ((const uint4*)bh)[0];
      uint4 u1 = ((const uint4*)bh)[1];
      uint4 w0 = ((const uint4*)bl)[0];
      uint4 w1 = ((const uint4*)bl)[1];
      *(uint4*)&Bs_hi[sr * LDT + skc] = u0;
      *(uint4*)&Bs_hi[sr * LDT + skc + 8] = u1;
      *(uint4*)&Bs_lo[sr * LDT + skc] = w0;
      *(uint4*)&Bs_lo[sr * LDT + skc + 8] = w1;
    }
    __syncthreads();

    // ---- fragments + MFMA ----
    bf16x8 ah[4], al[4], bh[4], bl[4];
#pragma unroll
    for (int nt = 0; nt < 4; nt++) {
      int nrow = nBase + nt * 16 + ml;
      bh[nt] = *(const bf16x8*)&Bs_hi[nrow * LDT + quad * 8];
      bl[nt] = *(const bf16x8*)&Bs_lo[nrow * LDT + quad * 8];
    }
#pragma unroll
    for (int mt = 0; mt < 4; mt++) {
      int mrow = mBase + mt * 16 + ml;
      ah[mt] = *(const bf16x8*)&As_hi[mrow * LDT + quad * 8];
      al[mt] = *(const bf16x8*)&As_lo[mrow * LDT + quad * 8];
    }
#pragma unroll
    for (int mt = 0; mt < 4; mt++)
#pragma unroll
      for (int nt = 0; nt < 4; nt++) {
        acc[mt][nt] = __builtin_amdgcn_mfma_f32_16x16x32_bf16(ah[mt], bh[nt], acc[mt][nt], 0, 0, 0);
        acc[mt][nt] = __builtin_amdgcn_mfma_f32_16x16x32_bf16(ah[mt], bl[nt], acc[mt][nt], 0, 0, 0);
        acc[mt][nt] = __builtin_amdgcn_mfma_f32_16x16x32_bf16(al[mt], bh[nt], acc[mt][nt], 0, 0, 0);
      }
    __syncthreads();
  }

  // ---- epilogue: C/D layout col=lane&15, row=quad*4+reg ----
#pragma unroll
  for (int nt = 0; nt < 4; nt++) {
    int col = colBase + nBase + nt * 16 + ml;
    float bv = bias ? bias[col] : 0.f;
#pragma unroll
    for (int mt = 0; mt < 4; mt++) {
      int row0 = rowBase + mBase + mt * 16 + quad * 4;
#pragma unroll
      for (int r = 0; r < 4; r++) {
        int grow = row0 + r;
        if (grow >= nrows) continue;
        float v = acc[mt][nt][r] + bv;
        if (relu) v = fmaxf(v, 0.f);
        Cmat[(size_t)grow * M + col] = v;
      }
    }
  }
}

// ---------------------------------------------------------------- launch

extern "C" void kernel_launch(void* const* d_in, const int* in_sizes, int n_in, void* d_out,
                              int out_size, void* d_ws, size_t ws_size, hipStream_t stream) {
  const float* x_self     = (const float*)d_in[0];
  const float* x_neighbor = (const float*)d_in[1];
  const void*  edge_index = d_in[2];
  const float* W_in_self  = (const float*)d_in[3];
  const float* b_in_self  = (const float*)d_in[4];
  const float* W_out_self = (const float*)d_in[5];
  const float* b_out_self = (const float*)d_in[6];
  const float* Wg1        = (const float*)d_in[7];
  const float* bg1        = (const float*)d_in[8];
  const float* Wg2        = (const float*)d_in[9];
  const float* bg2        = (const float*)d_in[10];
  const float* W_out      = (const float*)d_in[11];
  const float* b_out      = (const float*)d_in[12];
  float* out = (float*)d_out;

  char* ws = (char*)d_ws;
  size_t off = 0;
  auto alloc = [&](size_t bytes) -> void* {
    void* p = ws + off;
    off = (off + bytes + 255) & ~(size_t)255;
    return p;
  };
  int*   counts = (int*)alloc((size_t)NNODES * 4);
  int*   fillc  = (int*)alloc((size_t)NNODES * 4);
  int*   offs   = (int*)alloc((size_t)(NNODES + 1) * 4);
  int*   csr    = (int*)alloc((size_t)NEDGES * 4);
  int*   bsums  = (int*)alloc(4096);
  int*   flag   = (int*)alloc(256);
  float* dinv   = (float*)alloc((size_t)NNODES * 4);
  // split/transposed weights (bf16 hi/lo)
  unsigned short* wt1h = (unsigned short*)alloc(32768 * 2);  // W_in_self  K=128 M=256
  unsigned short* wt1l = (unsigned short*)alloc(32768 * 2);
  unsigned short* wt2h = (unsigned short*)alloc(49152 * 2);  // W_out_self K=384 M=128
  unsigned short* wt2l = (unsigned short*)alloc(49152 * 2);
  unsigned short* wt3h = (unsigned short*)alloc(32768 * 2);  // Wg1        K=128 M=256
  unsigned short* wt3l = (unsigned short*)alloc(32768 * 2);
  unsigned short* wt4h = (unsigned short*)alloc(32768 * 2);  // Wg2        K=256 M=128
  unsigned short* wt4l = (unsigned short*)alloc(32768 * 2);
  unsigned short* wt5h = (unsigned short*)alloc(65536 * 2);  // W_out      K=512 M=128
  unsigned short* wt5l = (unsigned short*)alloc(65536 * 2);
  float* bufA = (float*)alloc((size_t)NNODES * 256 * 4);
  float* bufB = (float*)alloc((size_t)NNODES * 256 * 4);
  (void)ws_size;

  const int nb = (NNODES + SCAN_TILE - 1) / SCAN_TILE;  // 98
  const int gridRows = (NNODES + BM - 1) / BM;          // 782

  detect_kernel<<<1, 64, 0, stream>>>((const unsigned int*)edge_index, flag);
  zero_int_kernel<<<(NNODES + 255) / 256, 256, 0, stream>>>(counts, NNODES);
  zero_int_kernel<<<(NNODES + 255) / 256, 256, 0, stream>>>(fillc, NNODES);
  hist_kernel<<<1024, 256, 0, stream>>>(edge_index, flag, counts);
  dinv_kernel<<<(NNODES + 255) / 256, 256, 0, stream>>>(counts, dinv);
  scan_reduce_kernel<<<nb, SCAN_B, 0, stream>>>(counts, bsums);
  scan_bsums_kernel<<<1, 64, 0, stream>>>(bsums, offs, nb);
  scan_write_kernel<<<nb, SCAN_B, 0, stream>>>(counts, bsums, offs);
  fill_kernel<<<1024, 256, 0, stream>>>(edge_index, flag, offs, fillc, csr);

  // weight split/transpose (tiny)
  wprep_kernel<<<(32768 + 255) / 256, 256, 0, stream>>>(W_in_self, 128, 256, wt1h, wt1l);
  wprep_kernel<<<(49152 + 255) / 256, 256, 0, stream>>>(W_out_self, 384, 128, wt2h, wt2l);
  wprep_kernel<<<(32768 + 255) / 256, 256, 0, stream>>>(Wg1, 128, 256, wt3h, wt3l);
  wprep_kernel<<<(32768 + 255) / 256, 256, 0, stream>>>(Wg2, 256, 128, wt4h, wt4l);
  wprep_kernel<<<(65536 + 255) / 256, 256, 0, stream>>>(W_out, 512, 128, wt5h, wt5l);

  // ---- dense self branch ----
  gemm_mfma_kernel<<<dim3(gridRows, 2), 256, 0, stream>>>(
      x_self, 128, nullptr, 0, nullptr, 0, wt1h, wt1l, 128, 256, b_in_self, bufA, 1, NNODES);
  gemm_mfma_kernel<<<dim3(gridRows, 1), 256, 0, stream>>>(
      x_self, 128, bufA, 256, nullptr, 0, wt2h, wt2l, 384, 128, b_out_self, out, 0, NNODES);

  // ---- GCN branch (A_norm @ (X W) == (A_norm @ X) W) ----
  float* aggx = bufA;                         // [N,128]
  float* g1   = bufB;                         // [N,256]
  float* xw2  = bufA;                         // [N,128]
  float* g2   = bufA + (size_t)NNODES * 128;  // [N,128]

  aggregate_kernel<<<NNODES / 4, 256, 0, stream>>>(x_neighbor, aggx, offs, csr, dinv, nullptr);
  gemm_mfma_kernel<<<dim3(gridRows, 2), 256, 0, stream>>>(
      aggx, 128, nullptr, 0, nullptr, 0, wt3h, wt3l, 128, 256, bg1, g1, 0, NNODES);
  gemm_mfma_kernel<<<dim3(gridRows, 1), 256, 0, stream>>>(
      g1, 256, nullptr, 0, nullptr, 0, wt4h, wt4l, 256, 128, nullptr, xw2, 0, NNODES);
  aggregate_kernel<<<NNODES / 4, 256, 0, stream>>>(xw2, g2, offs, csr, dinv, bg2);
  gemm_mfma_kernel<<<dim3(gridRows, 1), 256, 0, stream>>>(
      x_neighbor, 128, g1, 256, g2, 128, wt5h, wt5l, 512, 128, b_out,
      out + (size_t)NNODES * 128, 0, NNODES);
}

// Round 3
// 930.514 us; speedup vs baseline: 1.4051x; 1.1151x over previous
//
#include <hip/hip_runtime.h>
#include <cstdint>
#include <cstddef>

#define NNODES 100000
#define NEDGES 1600000
// D = 128, C = 128 (hard-coded below)

typedef short bf16x8 __attribute__((ext_vector_type(8)));
typedef float f32x4 __attribute__((ext_vector_type(4)));

// ---------------------------------------------------------------- bf16 split helpers

__device__ __forceinline__ unsigned short bf16_rne(float x) {
  unsigned int u = __float_as_uint(x);
  unsigned int r = u + 0x7FFFu + ((u >> 16) & 1u);
  return (unsigned short)(r >> 16);
}
__device__ __forceinline__ float bf16_to_f(unsigned short h) {
  return __uint_as_float(((unsigned int)h) << 16);
}

// ---------------------------------------------------------------- utilities

__global__ void zero_int_kernel(int* __restrict__ p, int n) {
  int i = blockIdx.x * blockDim.x + threadIdx.x;
  if (i < n) p[i] = 0;
}

// int64 vs int32 edge_index detection (high words all zero => int64)
__global__ void detect_kernel(const unsigned int* __restrict__ ei, int* __restrict__ flag) {
  unsigned int v = ei[2 * threadIdx.x + 1];
  unsigned long long b = __ballot(v != 0u);
  if (threadIdx.x == 0) *flag = (b == 0ull) ? 1 : 0;
}

__device__ __forceinline__ int edge_val(const void* ei, int is64, long long idx) {
  if (is64) return (int)((const long long*)ei)[idx];
  return ((const int*)ei)[idx];
}

// ---------------------------------------------------------------- degree / CSR

__global__ void hist_kernel(const void* __restrict__ ei, const int* __restrict__ flag,
                            int* __restrict__ counts) {
  const int is64 = *flag;
  for (long long e = (long long)blockIdx.x * blockDim.x + threadIdx.x; e < NEDGES;
       e += (long long)gridDim.x * blockDim.x) {
    int d = edge_val(ei, is64, NEDGES + e);
    atomicAdd(&counts[d], 1);
  }
}

__global__ void dinv_kernel(const int* __restrict__ counts, float* __restrict__ dinv) {
  int i = blockIdx.x * blockDim.x + threadIdx.x;
  if (i < NNODES) dinv[i] = rsqrtf((float)(counts[i] + 1));  // +1 self loop
}

#define SCAN_B 256
#define SCAN_TILE 1024

__global__ void scan_reduce_kernel(const int* __restrict__ counts, int* __restrict__ bsums) {
  __shared__ int sd[SCAN_B];
  int t = threadIdx.x;
  int base = blockIdx.x * SCAN_TILE + t * 4;
  int s = 0;
#pragma unroll
  for (int i = 0; i < 4; i++) {
    int idx = base + i;
    if (idx < NNODES) s += counts[idx];
  }
  sd[t] = s;
  __syncthreads();
  for (int o = SCAN_B / 2; o > 0; o >>= 1) {
    if (t < o) sd[t] += sd[t + o];
    __syncthreads();
  }
  if (t == 0) bsums[blockIdx.x] = sd[0];
}

__global__ void scan_bsums_kernel(int* __restrict__ bsums, int* __restrict__ offs, int nb) {
  if (threadIdx.x == 0 && blockIdx.x == 0) {
    int run = 0;
    for (int b = 0; b < nb; b++) {
      int v = bsums[b];
      bsums[b] = run;
      run += v;
    }
    offs[NNODES] = run;
  }
}

__global__ void scan_write_kernel(const int* __restrict__ counts, const int* __restrict__ bsums,
                                  int* __restrict__ offs) {
  __shared__ int sd[SCAN_B];
  int t = threadIdx.x;
  int base = blockIdx.x * SCAN_TILE + t * 4;
  int v[4];
  int s = 0;
#pragma unroll
  for (int i = 0; i < 4; i++) {
    int idx = base + i;
    v[i] = (idx < NNODES) ? counts[idx] : 0;
    s += v[i];
  }
  sd[t] = s;
  __syncthreads();
  for (int o = 1; o < SCAN_B; o <<= 1) {
    int x = (t >= o) ? sd[t - o] : 0;
    __syncthreads();
    sd[t] += x;
    __syncthreads();
  }
  int run = sd[t] - s + bsums[blockIdx.x];
#pragma unroll
  for (int i = 0; i < 4; i++) {
    int idx = base + i;
    if (idx < NNODES) {
      offs[idx] = run;
      run += v[i];
    }
  }
}

__global__ void fill_kernel(const void* __restrict__ ei, const int* __restrict__ flag,
                            const int* __restrict__ offs, int* __restrict__ fillc,
                            int* __restrict__ csr) {
  const int is64 = *flag;
  for (long long e = (long long)blockIdx.x * blockDim.x + threadIdx.x; e < NEDGES;
       e += (long long)gridDim.x * blockDim.x) {
    int s = edge_val(ei, is64, e);
    int d = edge_val(ei, is64, NEDGES + e);
    int pos = offs[d] + atomicAdd(&fillc[d], 1);
    csr[pos] = s;
  }
}

// ---------------------------------------------------------------- prescale
// y[i,:] = dinv[i] * x[i,:]

__global__ void prescale_kernel(const float* __restrict__ x, const float* __restrict__ dinv,
                                float* __restrict__ y) {
  int i = blockIdx.x * blockDim.x + threadIdx.x;  // over NNODES*64 float2
  if (i >= NNODES * 64) return;
  int row = i >> 6;
  float s = dinv[row];
  float2 v = ((const float2*)x)[i];
  v.x *= s;
  v.y *= s;
  ((float2*)y)[i] = v;
}

// ---------------------------------------------------------------- aggregation (gather)
// Input rows are PRE-SCALED: y_j = dinv[j]*x_j.
// out[i,:] = dinv[i] * (y_i + sum_{j in nbr(i)} y_j) + bias
// One wave per node, float2 per lane, 8-way unrolled gathers (4 accumulators)
// to keep ~8 row-gathers in flight per wave (latency-bound fix).

__global__ __launch_bounds__(256) void aggregate_kernel(
    const float* __restrict__ in, float* __restrict__ out, const int* __restrict__ offs,
    const int* __restrict__ csr, const float* __restrict__ dinv, const float* __restrict__ bias) {
  int node = blockIdx.x * 4 + (threadIdx.x >> 6);
  if (node >= NNODES) return;
  int c = (threadIdx.x & 63) * 2;
  int beg = offs[node], end = offs[node + 1];

  // self term (pre-scaled row)
  float2 a0 = *(const float2*)(in + (size_t)node * 128 + c);
  float2 a1 = make_float2(0.f, 0.f);
  float2 a2 = make_float2(0.f, 0.f);
  float2 a3 = make_float2(0.f, 0.f);

  int p = beg;
  for (; p + 8 <= end; p += 8) {
    int j0 = csr[p + 0], j1 = csr[p + 1], j2 = csr[p + 2], j3 = csr[p + 3];
    int j4 = csr[p + 4], j5 = csr[p + 5], j6 = csr[p + 6], j7 = csr[p + 7];
    float2 v0 = *(const float2*)(in + (size_t)j0 * 128 + c);
    float2 v1 = *(const float2*)(in + (size_t)j1 * 128 + c);
    float2 v2 = *(const float2*)(in + (size_t)j2 * 128 + c);
    float2 v3 = *(const float2*)(in + (size_t)j3 * 128 + c);
    float2 v4 = *(const float2*)(in + (size_t)j4 * 128 + c);
    float2 v5 = *(const float2*)(in + (size_t)j5 * 128 + c);
    float2 v6 = *(const float2*)(in + (size_t)j6 * 128 + c);
    float2 v7 = *(const float2*)(in + (size_t)j7 * 128 + c);
    a0.x += v0.x; a0.y += v0.y;
    a1.x += v1.x; a1.y += v1.y;
    a2.x += v2.x; a2.y += v2.y;
    a3.x += v3.x; a3.y += v3.y;
    a0.x += v4.x; a0.y += v4.y;
    a1.x += v5.x; a1.y += v5.y;
    a2.x += v6.x; a2.y += v6.y;
    a3.x += v7.x; a3.y += v7.y;
  }
  for (; p + 2 <= end; p += 2) {
    int j0 = csr[p], j1 = csr[p + 1];
    float2 v0 = *(const float2*)(in + (size_t)j0 * 128 + c);
    float2 v1 = *(const float2*)(in + (size_t)j1 * 128 + c);
    a0.x += v0.x; a0.y += v0.y;
    a1.x += v1.x; a1.y += v1.y;
  }
  if (p < end) {
    int j0 = csr[p];
    float2 v0 = *(const float2*)(in + (size_t)j0 * 128 + c);
    a0.x += v0.x; a0.y += v0.y;
  }

  float di = dinv[node];
  float2 r;
  r.x = di * (a0.x + a1.x + a2.x + a3.x);
  r.y = di * (a0.y + a1.y + a2.y + a3.y);
  if (bias) {
    r.x += bias[c];
    r.y += bias[c + 1];
  }
  *(float2*)(out + (size_t)node * 128 + c) = r;
}

// ---------------------------------------------------------------- weight prep
// W [K][M] fp32  ->  Wt_hi/Wt_lo [M][K] bf16 (transposed, split)

__global__ void wprep_kernel(const float* __restrict__ W, int K, int M,
                             unsigned short* __restrict__ th, unsigned short* __restrict__ tl) {
  int i = blockIdx.x * blockDim.x + threadIdx.x;
  if (i >= K * M) return;
  int k = i / M, m = i - k * M;
  float x = W[i];
  unsigned short h = bf16_rne(x);
  float lo = x - bf16_to_f(h);
  th[(size_t)m * K + k] = h;
  tl[(size_t)m * K + k] = bf16_rne(lo);
}

// ---------------------------------------------------------------- bf16x3 split MFMA GEMM
// C[n,M] = concat(A0,A1,A2) @ W (+row_scale)(+bias)(+relu), fp32 in/out, bf16 hi/lo split:
// x*w ~= xh*wh + xh*wl + xl*wh (fp32 MFMA accumulation). Error ~2^-16 relative.
// Block 128x128, BK=32, 4 waves each 64x64 (4x4 tiles of 16x16x32 MFMA).
// row_scale (optional): C[r,:] *= row_scale[r] before bias — used to fold the
// dinv pre-scale of the next aggregation into this GEMM's epilogue for free.

#define BM 128
#define BN 128
#define BK 32
#define LDT 40

__global__ __launch_bounds__(256) void gemm_mfma_kernel(
    const float* __restrict__ A0, int K0, const float* __restrict__ A1, int K1,
    const float* __restrict__ A2, int K2, const unsigned short* __restrict__ Bth,
    const unsigned short* __restrict__ Btl, int Ktot, int M, const float* __restrict__ bias,
    const float* __restrict__ row_scale, float* __restrict__ Cmat, int relu, int nrows) {
  __shared__ unsigned short As_hi[BM * LDT];
  __shared__ unsigned short As_lo[BM * LDT];
  __shared__ unsigned short Bs_hi[BN * LDT];
  __shared__ unsigned short Bs_lo[BN * LDT];

  const int tid = threadIdx.x;
  const int lane = tid & 63;
  const int wv = tid >> 6;
  const int mBase = (wv >> 1) * 64;
  const int nBase = (wv & 1) * 64;
  const int ml = lane & 15;
  const int quad = lane >> 4;
  const int rowBase = blockIdx.x * BM;
  const int colBase = blockIdx.y * BN;

  const int sr = tid >> 1;        // 0..127
  const int skc = (tid & 1) * 16; // 0 or 16

  f32x4 acc[4][4];
  const f32x4 zero = {0.f, 0.f, 0.f, 0.f};
#pragma unroll
  for (int i = 0; i < 4; i++)
#pragma unroll
    for (int j = 0; j < 4; j++) acc[i][j] = zero;

  for (int k0 = 0; k0 < Ktot; k0 += BK) {
    const float* Ap;
    int kl, Kp;
    if (k0 < K0) {
      Ap = A0; kl = k0; Kp = K0;
    } else if (k0 < K0 + K1) {
      Ap = A1; kl = k0 - K0; Kp = K1;
    } else {
      Ap = A2; kl = k0 - K0 - K1; Kp = K2;
    }
    {
      int gr = rowBase + sr;
      float4 v[4];
      if (gr < nrows) {
        const float4* src = (const float4*)(Ap + (size_t)gr * Kp + kl + skc);
#pragma unroll
        for (int i = 0; i < 4; i++) v[i] = src[i];
      } else {
#pragma unroll
        for (int i = 0; i < 4; i++) v[i] = make_float4(0.f, 0.f, 0.f, 0.f);
      }
      unsigned short hb[16], lb[16];
      const float* vf = (const float*)v;
#pragma unroll
      for (int i = 0; i < 16; i++) {
        float x = vf[i];
        unsigned short h = bf16_rne(x);
        hb[i] = h;
        lb[i] = bf16_rne(x - bf16_to_f(h));
      }
      *(uint4*)&As_hi[sr * LDT + skc] = *(uint4*)&hb[0];
      *(uint4*)&As_hi[sr * LDT + skc + 8] = *(uint4*)&hb[8];
      *(uint4*)&As_lo[sr * LDT + skc] = *(uint4*)&lb[0];
      *(uint4*)&As_lo[sr * LDT + skc + 8] = *(uint4*)&lb[8];

      const unsigned short* bh = Bth + (size_t)(colBase + sr) * Ktot + k0 + skc;
      const unsigned short* bl = Btl + (size_t)(colBase + sr) * Ktot + k0 + skc;
      uint4 u0 = ((const uint4*)bh)[0];
      uint4 u1 = ((const uint4*)bh)[1];
      uint4 w0 = ((const uint4*)bl)[0];
      uint4 w1 = ((const uint4*)bl)[1];
      *(uint4*)&Bs_hi[sr * LDT + skc] = u0;
      *(uint4*)&Bs_hi[sr * LDT + skc + 8] = u1;
      *(uint4*)&Bs_lo[sr * LDT + skc] = w0;
      *(uint4*)&Bs_lo[sr * LDT + skc + 8] = w1;
    }
    __syncthreads();

    bf16x8 ah[4], al[4], bh[4], bl[4];
#pragma unroll
    for (int nt = 0; nt < 4; nt++) {
      int nrow = nBase + nt * 16 + ml;
      bh[nt] = *(const bf16x8*)&Bs_hi[nrow * LDT + quad * 8];
      bl[nt] = *(const bf16x8*)&Bs_lo[nrow * LDT + quad * 8];
    }
#pragma unroll
    for (int mt = 0; mt < 4; mt++) {
      int mrow = mBase + mt * 16 + ml;
      ah[mt] = *(const bf16x8*)&As_hi[mrow * LDT + quad * 8];
      al[mt] = *(const bf16x8*)&As_lo[mrow * LDT + quad * 8];
    }
#pragma unroll
    for (int mt = 0; mt < 4; mt++)
#pragma unroll
      for (int nt = 0; nt < 4; nt++) {
        acc[mt][nt] = __builtin_amdgcn_mfma_f32_16x16x32_bf16(ah[mt], bh[nt], acc[mt][nt], 0, 0, 0);
        acc[mt][nt] = __builtin_amdgcn_mfma_f32_16x16x32_bf16(ah[mt], bl[nt], acc[mt][nt], 0, 0, 0);
        acc[mt][nt] = __builtin_amdgcn_mfma_f32_16x16x32_bf16(al[mt], bh[nt], acc[mt][nt], 0, 0, 0);
      }
    __syncthreads();
  }

  // epilogue: C/D layout col=lane&15, row=quad*4+reg
#pragma unroll
  for (int nt = 0; nt < 4; nt++) {
    int col = colBase + nBase + nt * 16 + ml;
    float bv = bias ? bias[col] : 0.f;
#pragma unroll
    for (int mt = 0; mt < 4; mt++) {
      int row0 = rowBase + mBase + mt * 16 + quad * 4;
#pragma unroll
      for (int r = 0; r < 4; r++) {
        int grow = row0 + r;
        if (grow >= nrows) continue;
        float v = acc[mt][nt][r];
        if (row_scale) v *= row_scale[grow];
        v += bv;
        if (relu) v = fmaxf(v, 0.f);
        Cmat[(size_t)grow * M + col] = v;
      }
    }
  }
}

// ---------------------------------------------------------------- launch

extern "C" void kernel_launch(void* const* d_in, const int* in_sizes, int n_in, void* d_out,
                              int out_size, void* d_ws, size_t ws_size, hipStream_t stream) {
  const float* x_self     = (const float*)d_in[0];
  const float* x_neighbor = (const float*)d_in[1];
  const void*  edge_index = d_in[2];
  const float* W_in_self  = (const float*)d_in[3];
  const float* b_in_self  = (const float*)d_in[4];
  const float* W_out_self = (const float*)d_in[5];
  const float* b_out_self = (const float*)d_in[6];
  const float* Wg1        = (const float*)d_in[7];
  const float* bg1        = (const float*)d_in[8];
  const float* Wg2        = (const float*)d_in[9];
  const float* bg2        = (const float*)d_in[10];
  const float* W_out      = (const float*)d_in[11];
  const float* b_out      = (const float*)d_in[12];
  float* out = (float*)d_out;

  char* ws = (char*)d_ws;
  size_t off = 0;
  auto alloc = [&](size_t bytes) -> void* {
    void* p = ws + off;
    off = (off + bytes + 255) & ~(size_t)255;
    return p;
  };
  int* counts = (int*)alloc((size_t)2 * NNODES * 4);  // counts + fillc contiguous
  int* fillc  = counts + NNODES;
  int*   offs   = (int*)alloc((size_t)(NNODES + 1) * 4);
  int*   csr    = (int*)alloc((size_t)NEDGES * 4);
  int*   bsums  = (int*)alloc(4096);
  int*   flag   = (int*)alloc(256);
  float* dinv   = (float*)alloc((size_t)NNODES * 4);
  unsigned short* wt1h = (unsigned short*)alloc(32768 * 2);  // W_in_self  K=128 M=256
  unsigned short* wt1l = (unsigned short*)alloc(32768 * 2);
  unsigned short* wt2h = (unsigned short*)alloc(49152 * 2);  // W_out_self K=384 M=128
  unsigned short* wt2l = (unsigned short*)alloc(49152 * 2);
  unsigned short* wt3h = (unsigned short*)alloc(32768 * 2);  // Wg1        K=128 M=256
  unsigned short* wt3l = (unsigned short*)alloc(32768 * 2);
  unsigned short* wt4h = (unsigned short*)alloc(32768 * 2);  // Wg2        K=256 M=128
  unsigned short* wt4l = (unsigned short*)alloc(32768 * 2);
  unsigned short* wt5h = (unsigned short*)alloc(65536 * 2);  // W_out      K=512 M=128
  unsigned short* wt5l = (unsigned short*)alloc(65536 * 2);
  float* bufA = (float*)alloc((size_t)NNODES * 256 * 4);
  float* bufB = (float*)alloc((size_t)NNODES * 256 * 4);
  (void)ws_size;

  const int nb = (NNODES + SCAN_TILE - 1) / SCAN_TILE;  // 98
  const int gridRows = (NNODES + BM - 1) / BM;          // 782

  detect_kernel<<<1, 64, 0, stream>>>((const unsigned int*)edge_index, flag);
  zero_int_kernel<<<(2 * NNODES + 255) / 256, 256, 0, stream>>>(counts, 2 * NNODES);
  hist_kernel<<<1024, 256, 0, stream>>>(edge_index, flag, counts);
  dinv_kernel<<<(NNODES + 255) / 256, 256, 0, stream>>>(counts, dinv);
  scan_reduce_kernel<<<nb, SCAN_B, 0, stream>>>(counts, bsums);
  scan_bsums_kernel<<<1, 64, 0, stream>>>(bsums, offs, nb);
  scan_write_kernel<<<nb, SCAN_B, 0, stream>>>(counts, bsums, offs);
  fill_kernel<<<1024, 256, 0, stream>>>(edge_index, flag, offs, fillc, csr);

  wprep_kernel<<<(32768 + 255) / 256, 256, 0, stream>>>(W_in_self, 128, 256, wt1h, wt1l);
  wprep_kernel<<<(49152 + 255) / 256, 256, 0, stream>>>(W_out_self, 384, 128, wt2h, wt2l);
  wprep_kernel<<<(32768 + 255) / 256, 256, 0, stream>>>(Wg1, 128, 256, wt3h, wt3l);
  wprep_kernel<<<(32768 + 255) / 256, 256, 0, stream>>>(Wg2, 256, 128, wt4h, wt4l);
  wprep_kernel<<<(65536 + 255) / 256, 256, 0, stream>>>(W_out, 512, 128, wt5h, wt5l);

  // ---- dense self branch ----
  gemm_mfma_kernel<<<dim3(gridRows, 2), 256, 0, stream>>>(
      x_self, 128, nullptr, 0, nullptr, 0, wt1h, wt1l, 128, 256, b_in_self, nullptr, bufA, 1,
      NNODES);
  gemm_mfma_kernel<<<dim3(gridRows, 1), 256, 0, stream>>>(
      x_self, 128, bufA, 256, nullptr, 0, wt2h, wt2l, 384, 128, b_out_self, nullptr, out, 0,
      NNODES);

  // ---- GCN branch (A_norm @ (X W) == (A_norm @ X) W) ----
  // Buffer timeline: ybuf=bufB[0:N*128] (consumed by agg1 before GEMM-3 overwrites bufB)
  float* ybuf = bufB;                         // [N,128] pre-scaled x_neighbor
  float* aggx = bufA;                         // [N,128] (bufA free after GEMM-2)
  float* g1   = bufB;                         // [N,256]
  float* xw2  = bufA;                         // [N,128] (aggx dead after GEMM-3)
  float* g2   = bufA + (size_t)NNODES * 128;  // [N,128]

  prescale_kernel<<<(NNODES * 64 + 255) / 256, 256, 0, stream>>>(x_neighbor, dinv, ybuf);
  aggregate_kernel<<<NNODES / 4, 256, 0, stream>>>(ybuf, aggx, offs, csr, dinv, nullptr);
  gemm_mfma_kernel<<<dim3(gridRows, 2), 256, 0, stream>>>(
      aggx, 128, nullptr, 0, nullptr, 0, wt3h, wt3l, 128, 256, bg1, nullptr, g1, 0, NNODES);
  // xw2 = (g1 @ Wg2) * dinv[row]  (pre-scale for agg2 folded into epilogue)
  gemm_mfma_kernel<<<dim3(gridRows, 1), 256, 0, stream>>>(
      g1, 256, nullptr, 0, nullptr, 0, wt4h, wt4l, 256, 128, nullptr, dinv, xw2, 0, NNODES);
  aggregate_kernel<<<NNODES / 4, 256, 0, stream>>>(xw2, g2, offs, csr, dinv, bg2);
  gemm_mfma_kernel<<<dim3(gridRows, 1), 256, 0, stream>>>(
      x_neighbor, 128, g1, 256, g2, 128, wt5h, wt5l, 512, 128, b_out, nullptr,
      out + (size_t)NNODES * 128, 0, NNODES);
}